// Round 10
// baseline (323.116 us; speedup 1.0000x reference)
//
#include <hip/hip_runtime.h>

#define B_ 2
#define L_ 4096
#define DMODEL 1024
#define DSTATE 128
#define DINNER 2048
#define NH 32
#define HD 64
#define DPROJ 4384
#define DPROJP 4480
#define NC 32
#define EPSF 1e-5f
#define ROWS (B_*L_)

typedef unsigned short u16;
typedef __attribute__((ext_vector_type(8))) short s8v;
typedef __attribute__((ext_vector_type(4))) float f4v;
typedef __attribute__((ext_vector_type(4))) int i4v;
typedef __attribute__((ext_vector_type(2))) int i2v;
typedef __attribute__((ext_vector_type(4))) float fl4;

static __device__ __forceinline__ float b2f(u16 u){
  unsigned int x = ((unsigned int)u) << 16;
  return __builtin_bit_cast(float, x);
}
static __device__ __forceinline__ u16 f2b(float f){
  unsigned int x = __builtin_bit_cast(unsigned int, f);
  unsigned int r = x + 0x7FFFu + ((x >> 16) & 1u);
  return (u16)(r >> 16);
}
static __device__ __forceinline__ float softplusf(float x){
  return (x > 20.f) ? x : log1pf(expf(x));
}
// async global->LDS, 16B per lane; LDS dest = wave-uniform base + lane*16
static __device__ __forceinline__ void gl_lds16(const u16* g, u16* l){
  __builtin_amdgcn_global_load_lds(
    (const __attribute__((address_space(1))) unsigned int*)g,
    (__attribute__((address_space(3))) unsigned int*)l, 16, 0, 0);
}
// swizzle for 256B-row (128 u16) LDS tiles: 16B slot ^= row&15 (bijective)
static __device__ __forceinline__ int swz(int row, int col){
  return row*128 + ((((col >> 3) ^ (row & 15)) << 3) | (col & 7));
}
// swizzle for 128B-row (64 u16) LDS tiles: 16B slot ^= row&7
static __device__ __forceinline__ int swz64(int row, int col){
  return row*64 + ((((col >> 3) ^ (row & 7)) << 3) | (col & 7));
}
// conv out_s swizzle: [128][64] u16, slot ^= (t>>3)&7 (column reads stride t by 8)
static __device__ __forceinline__ int osw(int t, int j){
  return t*64 + ((((j >> 3) ^ ((t >> 3) & 7)) << 3) | (j & 7));
}

// ---------------- debug: report ws_size if insufficient ----------------
__global__ void k_dbg(float* out, float v){ out[0] = v; }

// ---------------- weight packing (both weights, one kernel) ----------------
#define NW1 ((size_t)DPROJP*DMODEL)
#define NW2 ((size_t)DMODEL*DINNER)
__global__ __launch_bounds__(256) void k_pack(const float* __restrict__ W1, const float* __restrict__ W2,
                                              u16* __restrict__ W1b, u16* __restrict__ W2b){
  size_t i = (size_t)blockIdx.x*256 + threadIdx.x;
  if (i < NW1){
    size_t n = i / DMODEL;
    W1b[i] = (n < DPROJ) ? f2b(W1[i]) : (u16)0;
  } else if (i < NW1 + NW2){
    size_t j = i - NW1;
    W2b[j] = f2b(W2[j]);
  }
}

// ---------------- layernorm ----------------
__global__ __launch_bounds__(256) void k_ln(const float* __restrict__ x, const float* __restrict__ nw,
                                            const float* __restrict__ nb, u16* __restrict__ xn){
  int m = blockIdx.x; int tid = threadIdx.x;
  const float* row = x + (size_t)m*DMODEL;
  fl4 v = *(const fl4*)&row[tid*4];
  float s1 = v[0]+v[1]+v[2]+v[3];
  float s2 = v[0]*v[0]+v[1]*v[1]+v[2]*v[2]+v[3]*v[3];
  #pragma unroll
  for (int o=32;o;o>>=1){ s1 += __shfl_down(s1,o); s2 += __shfl_down(s2,o); }
  __shared__ float r1[4], r2[4];
  if ((tid&63)==0){ r1[tid>>6]=s1; r2[tid>>6]=s2; }
  __syncthreads();
  s1 = r1[0]+r1[1]+r1[2]+r1[3]; s2 = r2[0]+r2[1]+r2[2]+r2[3];
  float mu = s1 * (1.f/DMODEL);
  float var = s2 * (1.f/DMODEL) - mu*mu;
  float rs = rsqrtf(var + EPSF);
  u16* o = xn + (size_t)m*DMODEL + tid*4;
  #pragma unroll
  for (int k=0;k<4;k++)
    o[k] = f2b((v[k]-mu)*rs*nw[tid*4+k] + nb[tid*4+k]);
}

// ---------------- 128x128 bt-GEMM (in-proj, bf16 out), 2D grid ----------------
__global__ __launch_bounds__(256) void k_gemm_in(const u16* __restrict__ A, const u16* __restrict__ Bw,
                  u16* __restrict__ Cout, int K, int lda, int ldb, int ldc){
  __shared__ u16 smem[2*128*64];     // sA | sB ; reused as 128x128 C-stage
  u16* sA = smem;
  u16* sB = smem + 128*64;
  int tid = threadIdx.x;
  int ln = tid & 63, wid = tid >> 6;
  int wr = wid >> 1, wc = wid & 1;
  size_t m0 = (size_t)blockIdx.x * 128, n0 = (size_t)blockIdx.y * 128;
  int lrow = ln >> 3;                 // 0..7 within a segment
  f4v acc[4][4] = {};
  for (int k0 = 0; k0 < K; k0 += 64){
    #pragma unroll
    for (int i = 0; i < 4; ++i){
      int seg = wid*4 + i;            // 16 segments of 8 rows
      int row = seg*8 + lrow;
      int scol = ((ln & 7) ^ (row & 7)) * 8;   // inverse-swizzled global source slot
      gl_lds16(&A [(m0+row)*lda + k0 + scol], &sA[seg*512]);
      gl_lds16(&Bw[(n0+row)*ldb + k0 + scol], &sB[seg*512]);
    }
    __syncthreads();
    #pragma unroll
    for (int kk=0; kk<2; kk++){
      s8v af[4], bfr[4];
      #pragma unroll
      for (int t=0;t<4;t++){
        int col = kk*32 + (ln>>4)*8;
        af[t]  = *(const s8v*)&sA[swz64(wr*64+t*16+(ln&15), col)];
        bfr[t] = *(const s8v*)&sB[swz64(wc*64+t*16+(ln&15), col)];
      }
      #pragma unroll
      for (int mt=0;mt<4;mt++)
        #pragma unroll
        for (int nt=0;nt<4;nt++)
          acc[mt][nt] = __builtin_amdgcn_mfma_f32_16x16x32_bf16(af[mt], bfr[nt], acc[mt][nt], 0,0,0);
    }
    __syncthreads();
  }
  // stage C in LDS (u16), then fully-coalesced 16B stores
  #pragma unroll
  for (int mt=0;mt<4;mt++)
    #pragma unroll
    for (int nt=0;nt<4;nt++)
      #pragma unroll
      for (int j=0;j<4;j++){
        int m = wr*64 + mt*16 + (ln>>4)*4 + j;
        int n = wc*64 + nt*16 + (ln&15);
        smem[m*128 + n] = f2b(acc[mt][nt][j]);
      }
  __syncthreads();
  #pragma unroll
  for (int it = 0; it < 8; ++it){
    int idx = (tid + it*256)*8;     // u16 index in 128x128
    int row = idx >> 7, col = idx & 127;
    *(i4v*)&Cout[(m0+row)*ldc + n0 + col] = *(const i4v*)&smem[idx];
  }
}

// ---------------- 128x128 bt-GEMM (out-proj): f32 out + residual, 2D grid ----------------
__global__ __launch_bounds__(256) void k_gemm_out(const u16* __restrict__ A, const u16* __restrict__ Bw,
                  float* __restrict__ Cout, const float* __restrict__ resid,
                  int K, int lda, int ldb, int ldc){
  __shared__ u16 sA[128*64];
  __shared__ u16 sB[128*64];
  int tid = threadIdx.x;
  int ln = tid & 63, wid = tid >> 6;
  int wr = wid >> 1, wc = wid & 1;
  size_t m0 = (size_t)blockIdx.x * 128, n0 = (size_t)blockIdx.y * 128;
  int lrow = ln >> 3;
  f4v acc[4][4] = {};
  for (int k0 = 0; k0 < K; k0 += 64){
    #pragma unroll
    for (int i = 0; i < 4; ++i){
      int seg = wid*4 + i;
      int row = seg*8 + lrow;
      int scol = ((ln & 7) ^ (row & 7)) * 8;
      gl_lds16(&A [(m0+row)*lda + k0 + scol], &sA[seg*512]);
      gl_lds16(&Bw[(n0+row)*ldb + k0 + scol], &sB[seg*512]);
    }
    __syncthreads();
    #pragma unroll
    for (int kk=0; kk<2; kk++){
      s8v af[4], bfr[4];
      #pragma unroll
      for (int t=0;t<4;t++){
        int col = kk*32 + (ln>>4)*8;
        af[t]  = *(const s8v*)&sA[swz64(wr*64+t*16+(ln&15), col)];
        bfr[t] = *(const s8v*)&sB[swz64(wc*64+t*16+(ln&15), col)];
      }
      #pragma unroll
      for (int mt=0;mt<4;mt++)
        #pragma unroll
        for (int nt=0;nt<4;nt++)
          acc[mt][nt] = __builtin_amdgcn_mfma_f32_16x16x32_bf16(af[mt], bfr[nt], acc[mt][nt], 0,0,0);
    }
    __syncthreads();
  }
  #pragma unroll
  for (int mt=0;mt<4;mt++)
    #pragma unroll
    for (int nt=0;nt<4;nt++)
      #pragma unroll
      for (int j=0;j<4;j++){
        size_t m = m0 + wr*64 + mt*16 + (ln>>4)*4 + j;
        size_t n = n0 + wc*64 + nt*16 + (ln&15);
        Cout[m*ldc + n] = acc[mt][nt][j] + resid[m*ldc + n];
      }
}

// ---------------- conv4 + silu + dt + acum + split (dtg layout [b][h][L]) ----------------
__global__ __launch_bounds__(256) void k_conv(const u16* __restrict__ zx, const float* __restrict__ cw,
    const float* __restrict__ cb, const float* __restrict__ dtb, const float* __restrict__ A_log,
    u16* __restrict__ Xt, u16* __restrict__ Bln, u16* __restrict__ Bt,
    u16* __restrict__ Cln, float* __restrict__ dtg, float* __restrict__ acum){
  __shared__ u16 in_s[131*64];
  __shared__ u16 out_s[128*64];       // swizzled via osw()
  __shared__ float dt_s[128];
  __shared__ float a_s[128];
  int bid = blockIdx.x;
  int g = bid % 36;
  int c = (bid / 36) & 31;
  int b = bid / (36*32);
  int tid = threadIdx.x;
  int t0 = c*128;
  size_t rowb = (size_t)b*L_ + t0;
  for (int i8 = tid; i8 < 1048; i8 += 256){   // 131*64/8
    int r = i8 >> 3, j0 = (i8 & 7)*8;
    int t = t0 - 3 + r;
    i4v v;
    if (t >= 0) v = *(const i4v*)&zx[((size_t)b*L_ + t)*DPROJP + 2048 + g*64 + j0];
    else { v[0]=0; v[1]=0; v[2]=0; v[3]=0; }
    *(i4v*)&in_s[r*64 + j0] = v;
  }
  if (tid < 128){
    if (g < 32){
      float raw = b2f(zx[(rowb + tid)*DPROJP + (DPROJ - NH) + g]);
      float d = softplusf(raw + dtb[g]);
      dt_s[tid] = d;
      dtg[(size_t)(b*NH + g)*L_ + t0 + tid] = d;
      a_s[tid] = d * (-expf(A_log[g]));
    } else {
      dt_s[tid] = 0.f;
      a_s[tid] = 0.f;
    }
  }
  __syncthreads();
  // inclusive prefix-sum of a_s (uniform control flow; result discarded for g>=32)
  #pragma unroll
  for (int d = 1; d < 128; d <<= 1){
    float v = 0.f;
    if (tid < 128 && tid >= d) v = a_s[tid - d];
    __syncthreads();
    if (tid < 128) a_s[tid] += v;
    __syncthreads();
  }
  if (g < 32 && tid < 128)
    acum[((size_t)((b*NH + g)*NC + c))*128 + tid] = a_s[tid];
  {
    int j = tid & 63;
    int ch = g*64 + j;
    float w0 = cw[ch*4+0], w1 = cw[ch*4+1], w2 = cw[ch*4+2], w3 = cw[ch*4+3];
    float bia = cb[ch];
    int tb = tid >> 6;
    #pragma unroll
    for (int it = 0; it < 32; ++it){
      int t = tb + it*4;
      float a = bia
        + w0*b2f(in_s[(t+0)*64 + j]) + w1*b2f(in_s[(t+1)*64 + j])
        + w2*b2f(in_s[(t+2)*64 + j]) + w3*b2f(in_s[(t+3)*64 + j]);
      out_s[osw(t, j)] = f2b(a / (1.f + __expf(-a)));
    }
  }
  __syncthreads();
  if (g < 32){
    for (int i = tid; i < 1024; i += 256){      // 16B columns of Xt
      int j = i >> 4, tb = (i & 15)*8;
      i4v o; u16* ou = (u16*)&o;
      #pragma unroll
      for (int k = 0; k < 8; ++k)
        ou[k] = f2b(b2f(out_s[osw(tb + k, j)]) * dt_s[tb + k]);
      *(i4v*)&Xt[((size_t)((b*NH + g)*HD + j))*L_ + t0 + tb] = o;
    }
  } else {
    int q = g - 32;
    for (int i = tid; i < 1024; i += 256){
      int t = i >> 3, j0 = (i & 7)*8;
      i4v v = *(const i4v*)&out_s[osw(t, j0)];
      if (q < 2) *(i4v*)&Bln[(rowb + t)*DSTATE + q*64 + j0] = v;
      else       *(i4v*)&Cln[(rowb + t)*DSTATE + (q-2)*64 + j0] = v;
    }
    if (q < 2){
      for (int i = tid; i < 1024; i += 256){
        int j = i >> 4, tb = (i & 15)*8;
        i4v o; u16* ou = (u16*)&o;
        #pragma unroll
        for (int k = 0; k < 8; ++k) ou[k] = out_s[osw(tb + k, j)];
        *(i4v*)&Bt[((size_t)(b*DSTATE + q*64 + j))*L_ + t0 + tb] = o;
      }
    }
  }
}

// ---------------- per-chunk states, 4 heads per block (B staged once) ----------------
__global__ __launch_bounds__(256) void k_states(const u16* __restrict__ Xt, const u16* __restrict__ Bt,
    const float* __restrict__ acum, u16* __restrict__ states){
  __shared__ u16 sX[64*128];
  __shared__ u16 sB[128*128];
  __shared__ float dec[128];
  int bid = blockIdx.x;           // ((b*NC + c)*8 + hg)
  int hg = bid & 7, c = (bid >> 3) & 31, b = bid >> 8;
  int tid = threadIdx.x;
  int ln = tid & 63, wid = tid >> 6;
  int wr = wid >> 1, wc = wid & 1;
  const u16* btb = Bt + (size_t)(b*DSTATE)*L_ + c*128;
  for (int i = tid*8; i < 128*128; i += 256*8){
    int n = i >> 7, l0 = i & 127;
    *(i4v*)&sB[swz(n, l0)] = *(const i4v*)&btb[(size_t)n*L_ + l0];
  }
  for (int hh = 0; hh < 4; ++hh){
    int h = hg*4 + hh;
    const float* acg = acum + ((size_t)((b*NH + h)*NC + c))*128;
    if (tid < 128) dec[tid] = __expf(acg[127] - acg[tid]);
    __syncthreads();               // dec+sB ready; prev iter's MFMA reads of sX done
    const u16* xtb = Xt + ((size_t)((b*NH + h)*HD))*L_ + c*128;
    for (int i = tid*8; i < 64*128; i += 256*8){
      int p = i >> 7, l0 = i & 127;
      i4v v = *(const i4v*)&xtb[(size_t)p*L_ + l0];
      const u16* vu = (const u16*)&v;
      i4v o; u16* ou = (u16*)&o;
      #pragma unroll
      for (int j = 0; j < 8; ++j) ou[j] = f2b(b2f(vu[j]) * dec[l0 + j]);
      *(i4v*)&sX[swz(p, l0)] = o;
    }
    __syncthreads();
    f4v acc[2][4] = {};
    #pragma unroll
    for (int kk = 0; kk < 4; ++kk){
      s8v af[2], bfr[4];
      int col = kk*32 + (ln>>4)*8;
      #pragma unroll
      for (int t = 0; t < 2; ++t)
        af[t] = *(const s8v*)&sX[swz(wr*32 + t*16 + (ln&15), col)];
      #pragma unroll
      for (int t = 0; t < 4; ++t)
        bfr[t] = *(const s8v*)&sB[swz(wc*64 + t*16 + (ln&15), col)];
      #pragma unroll
      for (int mt = 0; mt < 2; ++mt)
        #pragma unroll
        for (int nt = 0; nt < 4; ++nt)
          acc[mt][nt] = __builtin_amdgcn_mfma_f32_16x16x32_bf16(af[mt], bfr[nt], acc[mt][nt], 0,0,0);
    }
    u16* out = states + ((size_t)((b*NC + c)*NH + h))*(HD*DSTATE);
    #pragma unroll
    for (int mt = 0; mt < 2; ++mt)
      #pragma unroll
      for (int nt = 0; nt < 4; ++nt){
        int n = wc*64 + nt*16 + (ln&15);
        #pragma unroll
        for (int j = 0; j < 4; ++j){
          int p = wr*32 + mt*16 + (ln>>4)*4 + j;
          out[(size_t)p*DSTATE + n] = f2b(acc[mt][nt][j]);
        }
      }
  }
}

// ---------------- inter-chunk scan (in place, bf16), element-parallel, batched loads ----------------
__global__ __launch_bounds__(256) void k_scan(u16* __restrict__ states, const float* __restrict__ acum){
  int bid = blockIdx.x;            // (b*NH + h)*8 + eb
  int eb = bid & 7;
  int hb = bid >> 3;
  int h = hb & 31, b = hb >> 5;
  int tid = threadIdx.x;
  size_t ebase = (size_t)eb*1024 + (size_t)tid*4;
  size_t hoff = ((size_t)(b*NC*NH + h))*(HD*DSTATE) + ebase;
  float dec[NC];
  #pragma unroll
  for (int c = 0; c < NC; ++c)
    dec[c] = __expf(acum[((size_t)((b*NH + h)*NC + c))*128 + 127]);
  i2v w[NC];
  #pragma unroll
  for (int c = 0; c < NC; ++c)
    w[c] = *(const i2v*)&states[(size_t)c*(NH*HD*DSTATE) + hoff];
  float run[4] = {0.f, 0.f, 0.f, 0.f};
  #pragma unroll
  for (int c = 0; c < NC; ++c){
    u16* wu = (u16*)&w[c];
    #pragma unroll
    for (int j = 0; j < 4; ++j){
      float tmp = b2f(wu[j]);
      wu[j] = f2b(run[j]);
      run[j] = run[j]*dec[c] + tmp;
    }
  }
  #pragma unroll
  for (int c = 0; c < NC; ++c)
    *(i2v*)&states[(size_t)c*(NH*HD*DSTATE) + hoff] = w[c];
}

// ---------------- Y, 4 heads per block: S_raw = C·B^T computed ONCE ----------------
__global__ __launch_bounds__(256) void k_y(const u16* __restrict__ Cln, const u16* __restrict__ Bln,
    const u16* __restrict__ Xt, const u16* __restrict__ prev, const float* __restrict__ acum,
    const float* __restrict__ dtg, const float* __restrict__ Dp, u16* __restrict__ Y){
  __shared__ u16 sC[128*128];
  __shared__ u16 sBS[128*128];   // B tile, then reused per head to hold masked S
  __shared__ float dt_s[128];
  int bid = blockIdx.x;           // ((b*NC + c)*8 + hg)
  int hg = bid & 7, c = (bid >> 3) & 31, b = bid >> 8;
  int tid = threadIdx.x;
  size_t rowb = (size_t)b*L_ + c*128;
  for (int i = tid*8; i < 128*128; i += 256*8){
    int row = i >> 7, col = i & 127;
    int d = swz(row, col);
    *(i4v*)&sC[d]  = *(const i4v*)&Cln[(rowb + row)*DSTATE + col];
    *(i4v*)&sBS[d] = *(const i4v*)&Bln[(rowb + row)*DSTATE + col];
  }
  __syncthreads();
  int ln = tid & 63, wid = tid >> 6;
  int wr = wid >> 1, wc = wid & 1;
  // S_raw = C·B^T, once per (b,c) group
  f4v aS[4][4] = {};
  #pragma unroll
  for (int kk = 0; kk < 4; ++kk){
    s8v af[4], bfr[4];
    #pragma unroll
    for (int t = 0; t < 4; ++t){
      int col = kk*32 + (ln>>4)*8;
      af[t]  = *(const s8v*)&sC [swz(wr*64 + t*16 + (ln&15), col)];
      bfr[t] = *(const s8v*)&sBS[swz(wc*64 + t*16 + (ln&15), col)];
    }
    #pragma unroll
    for (int mt = 0; mt < 4; ++mt)
      #pragma unroll
      for (int nt = 0; nt < 4; ++nt)
        aS[mt][nt] = __builtin_amdgcn_mfma_f32_16x16x32_bf16(af[mt], bfr[nt], aS[mt][nt], 0,0,0);
  }
  for (int hh = 0; hh < 4; ++hh){
    int h = hg*4 + hh;
    const float* acg = acum + ((size_t)((b*NH + h)*NC + c))*128;
    float Dh = Dp[h];
    if (tid < 128) dt_s[tid] = dtg[(size_t)(b*NH + h)*L_ + c*128 + tid];
    __syncthreads();   // hh=0: everyone done reading sBS(B); hh>0: prev PV done reading sBS
    #pragma unroll
    for (int mt = 0; mt < 4; ++mt)
      #pragma unroll
      for (int nt = 0; nt < 4; ++nt){
        int s = wc*64 + nt*16 + (ln&15);
        float as = acg[s];
        #pragma unroll
        for (int j = 0; j < 4; ++j){
          int l = wr*64 + mt*16 + (ln>>4)*4 + j;
          float v = 0.f;
          if (s <= l){
            v = aS[mt][nt][j] * __expf(acg[l] - as);
            if (s == l) v += Dh / dt_s[l];   // folds D*xs into the diagonal
          }
          sBS[swz(l, s)] = f2b(v);
        }
      }
    __syncthreads();
    const u16* xtb = Xt + ((size_t)((b*NH + h)*HD))*L_ + c*128;
    const u16* pv = prev + ((size_t)((b*NC + c)*NH + h))*(HD*DSTATE);
    f4v aD[4][2] = {}, aO[4][2] = {};
    #pragma unroll
    for (int kk = 0; kk < 4; ++kk){
      s8v aSf[4], aCf[4], bXf[2], bPf[2];
      #pragma unroll
      for (int t = 0; t < 4; ++t){
        int col = kk*32 + (ln>>4)*8;
        int row = wr*64 + t*16 + (ln&15);
        aSf[t] = *(const s8v*)&sBS[swz(row, col)];
        aCf[t] = *(const s8v*)&sC[swz(row, col)];
      }
      #pragma unroll
      for (int t = 0; t < 2; ++t){
        int p = wc*32 + t*16 + (ln&15);
        int ko = kk*32 + (ln>>4)*8;
        bXf[t] = *(const s8v*)&xtb[(size_t)p*L_ + ko];
        bPf[t] = *(const s8v*)&pv[(size_t)p*DSTATE + ko];
      }
      #pragma unroll
      for (int mt = 0; mt < 4; ++mt)
        #pragma unroll
        for (int nt = 0; nt < 2; ++nt){
          aD[mt][nt] = __builtin_amdgcn_mfma_f32_16x16x32_bf16(aSf[mt], bXf[nt], aD[mt][nt], 0,0,0);
          aO[mt][nt] = __builtin_amdgcn_mfma_f32_16x16x32_bf16(aCf[mt], bPf[nt], aO[mt][nt], 0,0,0);
        }
    }
    #pragma unroll
    for (int mt = 0; mt < 4; ++mt)
      #pragma unroll
      for (int nt = 0; nt < 2; ++nt){
        int p = wc*32 + nt*16 + (ln&15);
        #pragma unroll
        for (int j = 0; j < 4; ++j){
          int l = wr*64 + mt*16 + (ln>>4)*4 + j;
          float ex = __expf(acg[l]);
          Y[(rowb + l)*DINNER + h*HD + p] = f2b(aD[mt][nt][j] + ex*aO[mt][nt][j]);
        }
      }
  }
}

// ---------------- gating + RMSNorm (in place on Y) ----------------
__global__ __launch_bounds__(256) void k_gate(u16* __restrict__ Y, const u16* __restrict__ zx,
                                              const float* __restrict__ rw){
  size_t m = blockIdx.x; int tid = threadIdx.x;
  u16* yrow = Y + m*DINNER + tid*8;
  const u16* zrow = zx + m*DPROJP + tid*8;
  i4v yv = *(const i4v*)yrow;
  i4v zv = *(const i4v*)zrow;
  const u16* yu = (const u16*)&yv;
  const u16* zu = (const u16*)&zv;
  float yg[8]; float ss = 0.f;
  #pragma unroll
  for (int k = 0; k < 8; ++k){
    float z = b2f(zu[k]);
    float g = z / (1.f + __expf(-z));
    float v = b2f(yu[k]) * g;
    yg[k] = v; ss += v*v;
  }
  #pragma unroll
  for (int o = 32; o; o >>= 1) ss += __shfl_down(ss, o);
  __shared__ float r[4];
  if ((tid&63) == 0) r[tid>>6] = ss;
  __syncthreads();
  ss = r[0]+r[1]+r[2]+r[3];
  float rstd = rsqrtf(ss*(1.f/DINNER) + EPSF);
  #pragma unroll
  for (int k = 0; k < 8; ++k)
    yrow[k] = f2b(yg[k]*rstd*rw[tid*8+k]);
}

// ---------------- launch ----------------
extern "C" void kernel_launch(void* const* d_in, const int* in_sizes, int n_in,
                              void* d_out, int out_size, void* d_ws, size_t ws_size,
                              hipStream_t stream){
  const float* x        = (const float*)d_in[0];
  const float* norm_w   = (const float*)d_in[1];
  const float* norm_b   = (const float*)d_in[2];
  const float* in_proj  = (const float*)d_in[3];
  const float* conv_w   = (const float*)d_in[4];
  const float* conv_b   = (const float*)d_in[5];
  const float* dt_bias  = (const float*)d_in[6];
  const float* A_log    = (const float*)d_in[7];
  const float* Dp       = (const float*)d_in[8];
  const float* rms_w    = (const float*)d_in[9];
  const float* out_proj = (const float*)d_in[10];

  char* ws = (char*)d_ws;
  size_t off = 0;
  auto alloc = [&](size_t bytes) -> void* {
    void* p = ws + off;
    off += (bytes + 255) & ~(size_t)255;
    return p;
  };
  u16*   w1b    = (u16*)  alloc((size_t)DPROJP*DMODEL*2);   //  9.2 MB
  u16*   w2b    = (u16*)  alloc((size_t)DMODEL*DINNER*2);   //  4.2 MB
  u16*   xn     = (u16*)  alloc((size_t)ROWS*DMODEL*2);     // 16.8 MB
  u16*   zx     = (u16*)  alloc((size_t)ROWS*DPROJP*2);     // 73.4 MB
  u16*   Xt     = (u16*)  alloc((size_t)B_*NH*HD*L_*2);     // 33.6 MB
  u16*   Bln    = (u16*)  alloc((size_t)ROWS*DSTATE*2);     //  2.1 MB
  u16*   Bt     = (u16*)  alloc((size_t)B_*DSTATE*L_*2);    //  2.1 MB
  u16*   Cln    = (u16*)  alloc((size_t)ROWS*DSTATE*2);     //  2.1 MB
  float* dtg    = (float*)alloc((size_t)B_*NH*L_*4);        //  1.0 MB
  float* acum   = (float*)alloc((size_t)B_*NH*NC*128*4);    //  1.0 MB
  u16*   Y      = (u16*)  alloc((size_t)ROWS*DINNER*2);     // 33.6 MB
  // states/prev (bf16, 33.6 MB) lives in d_out: dead before final GEMM writes d_out.
  u16* states = (u16*)d_out;
  if (off > ws_size){
    k_dbg<<<1, 1, 0, stream>>>((float*)d_out, (float)ws_size);
    return;
  }

  k_pack<<<dim3((unsigned)((NW1 + NW2 + 255)/256)), 256, 0, stream>>>(in_proj, out_proj, w1b, w2b);
  k_ln<<<dim3(ROWS), 256, 0, stream>>>(x, norm_w, norm_b, xn);
  k_gemm_in<<<dim3(ROWS/128, DPROJP/128), 256, 0, stream>>>(xn, w1b, zx,
                                                            DMODEL, DMODEL, DMODEL, DPROJP);
  k_conv<<<dim3(B_*NC*36), 256, 0, stream>>>(zx, conv_w, conv_b, dt_bias, A_log,
                                             Xt, Bln, Bt, Cln, dtg, acum);
  k_states<<<dim3(B_*NC*(NH/4)), 256, 0, stream>>>(Xt, Bt, acum, states);
  k_scan<<<dim3(B_*NH*8), 256, 0, stream>>>(states, acum);
  k_y<<<dim3(B_*NC*(NH/4)), 256, 0, stream>>>(Cln, Bln, Xt, states, acum, dtg, Dp, Y);
  k_gate<<<dim3(ROWS), 256, 0, stream>>>(Y, zx, rms_w);
  k_gemm_out<<<dim3(ROWS/128, DMODEL/128), 256, 0, stream>>>(Y, w2b, (float*)d_out, x,
                                                             DINNER, DINNER, DINNER, DMODEL);
}

// Round 11
// 301.617 us; speedup vs baseline: 1.0713x; 1.0713x over previous
//
#include <hip/hip_runtime.h>

#define B_ 2
#define L_ 4096
#define DMODEL 1024
#define DSTATE 128
#define DINNER 2048
#define NH 32
#define HD 64
#define DPROJ 4384
#define DPROJP 4480
#define NC 32
#define EPSF 1e-5f
#define ROWS (B_*L_)

typedef unsigned short u16;
typedef __attribute__((ext_vector_type(8))) short s8v;
typedef __attribute__((ext_vector_type(4))) float f4v;
typedef __attribute__((ext_vector_type(4))) int i4v;
typedef __attribute__((ext_vector_type(2))) int i2v;
typedef __attribute__((ext_vector_type(4))) float fl4;

static __device__ __forceinline__ float b2f(u16 u){
  unsigned int x = ((unsigned int)u) << 16;
  return __builtin_bit_cast(float, x);
}
static __device__ __forceinline__ u16 f2b(float f){
  unsigned int x = __builtin_bit_cast(unsigned int, f);
  unsigned int r = x + 0x7FFFu + ((x >> 16) & 1u);
  return (u16)(r >> 16);
}
static __device__ __forceinline__ float softplusf(float x){
  return (x > 20.f) ? x : log1pf(expf(x));
}
// async global->LDS, 16B per lane; LDS dest = wave-uniform base + lane*16
static __device__ __forceinline__ void gl_lds16(const u16* g, u16* l){
  __builtin_amdgcn_global_load_lds(
    (const __attribute__((address_space(1))) unsigned int*)g,
    (__attribute__((address_space(3))) unsigned int*)l, 16, 0, 0);
}
// swizzle for 256B-row (128 u16) LDS tiles: 16B slot ^= row&15 (bijective)
static __device__ __forceinline__ int swz(int row, int col){
  return row*128 + ((((col >> 3) ^ (row & 15)) << 3) | (col & 7));
}
// swizzle for 128B-row (64 u16) LDS tiles: 16B slot ^= row&7
static __device__ __forceinline__ int swz64(int row, int col){
  return row*64 + ((((col >> 3) ^ (row & 7)) << 3) | (col & 7));
}
// conv out_s swizzle: [128][64] u16, slot ^= (t>>3)&7 (column reads stride t by 8)
static __device__ __forceinline__ int osw(int t, int j){
  return t*64 + ((((j >> 3) ^ ((t >> 3) & 7)) << 3) | (j & 7));
}

// ---------------- debug: report ws_size if insufficient ----------------
__global__ void k_dbg(float* out, float v){ out[0] = v; }

// ---------------- weight packing (both weights, one kernel) ----------------
#define NW1 ((size_t)DPROJP*DMODEL)
#define NW2 ((size_t)DMODEL*DINNER)
__global__ __launch_bounds__(256) void k_pack(const float* __restrict__ W1, const float* __restrict__ W2,
                                              u16* __restrict__ W1b, u16* __restrict__ W2b){
  size_t i = (size_t)blockIdx.x*256 + threadIdx.x;
  if (i < NW1){
    size_t n = i / DMODEL;
    W1b[i] = (n < DPROJ) ? f2b(W1[i]) : (u16)0;
  } else if (i < NW1 + NW2){
    size_t j = i - NW1;
    W2b[j] = f2b(W2[j]);
  }
}

// ---------------- layernorm ----------------
__global__ __launch_bounds__(256) void k_ln(const float* __restrict__ x, const float* __restrict__ nw,
                                            const float* __restrict__ nb, u16* __restrict__ xn){
  int m = blockIdx.x; int tid = threadIdx.x;
  const float* row = x + (size_t)m*DMODEL;
  fl4 v = *(const fl4*)&row[tid*4];
  float s1 = v[0]+v[1]+v[2]+v[3];
  float s2 = v[0]*v[0]+v[1]*v[1]+v[2]*v[2]+v[3]*v[3];
  #pragma unroll
  for (int o=32;o;o>>=1){ s1 += __shfl_down(s1,o); s2 += __shfl_down(s2,o); }
  __shared__ float r1[4], r2[4];
  if ((tid&63)==0){ r1[tid>>6]=s1; r2[tid>>6]=s2; }
  __syncthreads();
  s1 = r1[0]+r1[1]+r1[2]+r1[3]; s2 = r2[0]+r2[1]+r2[2]+r2[3];
  float mu = s1 * (1.f/DMODEL);
  float var = s2 * (1.f/DMODEL) - mu*mu;
  float rs = rsqrtf(var + EPSF);
  u16* o = xn + (size_t)m*DMODEL + tid*4;
  #pragma unroll
  for (int k=0;k<4;k++)
    o[k] = f2b((v[k]-mu)*rs*nw[tid*4+k] + nb[tid*4+k]);
}

// ---------------- 128x128 bt-GEMM (in-proj, bf16 out), 2D grid ----------------
__global__ __launch_bounds__(256) void k_gemm_in(const u16* __restrict__ A, const u16* __restrict__ Bw,
                  u16* __restrict__ Cout, int K, int lda, int ldb, int ldc){
  __shared__ u16 smem[2*128*64];     // sA | sB ; reused as 128x128 C-stage
  u16* sA = smem;
  u16* sB = smem + 128*64;
  int tid = threadIdx.x;
  int ln = tid & 63, wid = tid >> 6;
  int wr = wid >> 1, wc = wid & 1;
  size_t m0 = (size_t)blockIdx.x * 128, n0 = (size_t)blockIdx.y * 128;
  int lrow = ln >> 3;                 // 0..7 within a segment
  f4v acc[4][4] = {};
  for (int k0 = 0; k0 < K; k0 += 64){
    #pragma unroll
    for (int i = 0; i < 4; ++i){
      int seg = wid*4 + i;            // 16 segments of 8 rows
      int row = seg*8 + lrow;
      int scol = ((ln & 7) ^ (row & 7)) * 8;   // inverse-swizzled global source slot
      gl_lds16(&A [(m0+row)*lda + k0 + scol], &sA[seg*512]);
      gl_lds16(&Bw[(n0+row)*ldb + k0 + scol], &sB[seg*512]);
    }
    __syncthreads();
    #pragma unroll
    for (int kk=0; kk<2; kk++){
      s8v af[4], bfr[4];
      #pragma unroll
      for (int t=0;t<4;t++){
        int col = kk*32 + (ln>>4)*8;
        af[t]  = *(const s8v*)&sA[swz64(wr*64+t*16+(ln&15), col)];
        bfr[t] = *(const s8v*)&sB[swz64(wc*64+t*16+(ln&15), col)];
      }
      #pragma unroll
      for (int mt=0;mt<4;mt++)
        #pragma unroll
        for (int nt=0;nt<4;nt++)
          acc[mt][nt] = __builtin_amdgcn_mfma_f32_16x16x32_bf16(af[mt], bfr[nt], acc[mt][nt], 0,0,0);
    }
    __syncthreads();
  }
  // stage C in LDS (u16), then fully-coalesced 16B stores
  #pragma unroll
  for (int mt=0;mt<4;mt++)
    #pragma unroll
    for (int nt=0;nt<4;nt++)
      #pragma unroll
      for (int j=0;j<4;j++){
        int m = wr*64 + mt*16 + (ln>>4)*4 + j;
        int n = wc*64 + nt*16 + (ln&15);
        smem[m*128 + n] = f2b(acc[mt][nt][j]);
      }
  __syncthreads();
  #pragma unroll
  for (int it = 0; it < 8; ++it){
    int idx = (tid + it*256)*8;     // u16 index in 128x128
    int row = idx >> 7, col = idx & 127;
    *(i4v*)&Cout[(m0+row)*ldc + n0 + col] = *(const i4v*)&smem[idx];
  }
}

// ---------------- 128x128 bt-GEMM (out-proj): f32 out + residual, 2D grid ----------------
__global__ __launch_bounds__(256) void k_gemm_out(const u16* __restrict__ A, const u16* __restrict__ Bw,
                  float* __restrict__ Cout, const float* __restrict__ resid,
                  int K, int lda, int ldb, int ldc){
  __shared__ u16 sA[128*64];
  __shared__ u16 sB[128*64];
  int tid = threadIdx.x;
  int ln = tid & 63, wid = tid >> 6;
  int wr = wid >> 1, wc = wid & 1;
  size_t m0 = (size_t)blockIdx.x * 128, n0 = (size_t)blockIdx.y * 128;
  int lrow = ln >> 3;
  f4v acc[4][4] = {};
  for (int k0 = 0; k0 < K; k0 += 64){
    #pragma unroll
    for (int i = 0; i < 4; ++i){
      int seg = wid*4 + i;
      int row = seg*8 + lrow;
      int scol = ((ln & 7) ^ (row & 7)) * 8;
      gl_lds16(&A [(m0+row)*lda + k0 + scol], &sA[seg*512]);
      gl_lds16(&Bw[(n0+row)*ldb + k0 + scol], &sB[seg*512]);
    }
    __syncthreads();
    #pragma unroll
    for (int kk=0; kk<2; kk++){
      s8v af[4], bfr[4];
      #pragma unroll
      for (int t=0;t<4;t++){
        int col = kk*32 + (ln>>4)*8;
        af[t]  = *(const s8v*)&sA[swz64(wr*64+t*16+(ln&15), col)];
        bfr[t] = *(const s8v*)&sB[swz64(wc*64+t*16+(ln&15), col)];
      }
      #pragma unroll
      for (int mt=0;mt<4;mt++)
        #pragma unroll
        for (int nt=0;nt<4;nt++)
          acc[mt][nt] = __builtin_amdgcn_mfma_f32_16x16x32_bf16(af[mt], bfr[nt], acc[mt][nt], 0,0,0);
    }
    __syncthreads();
  }
  #pragma unroll
  for (int mt=0;mt<4;mt++)
    #pragma unroll
    for (int nt=0;nt<4;nt++)
      #pragma unroll
      for (int j=0;j<4;j++){
        size_t m = m0 + wr*64 + mt*16 + (ln>>4)*4 + j;
        size_t n = n0 + wc*64 + nt*16 + (ln&15);
        Cout[m*ldc + n] = acc[mt][nt][j] + resid[m*ldc + n];
      }
}

// ---------------- conv4 + silu + dt + acum + split (dtg layout [b][h][L]) ----------------
__global__ __launch_bounds__(256) void k_conv(const u16* __restrict__ zx, const float* __restrict__ cw,
    const float* __restrict__ cb, const float* __restrict__ dtb, const float* __restrict__ A_log,
    u16* __restrict__ Xt, u16* __restrict__ Bln, u16* __restrict__ Bt,
    u16* __restrict__ Cln, float* __restrict__ dtg, float* __restrict__ acum){
  __shared__ u16 in_s[131*64];
  __shared__ u16 out_s[128*64];       // swizzled via osw()
  __shared__ float dt_s[128];
  __shared__ float a_s[128];
  int bid = blockIdx.x;
  int g = bid % 36;
  int c = (bid / 36) & 31;
  int b = bid / (36*32);
  int tid = threadIdx.x;
  int t0 = c*128;
  size_t rowb = (size_t)b*L_ + t0;
  for (int i8 = tid; i8 < 1048; i8 += 256){   // 131*64/8
    int r = i8 >> 3, j0 = (i8 & 7)*8;
    int t = t0 - 3 + r;
    i4v v;
    if (t >= 0) v = *(const i4v*)&zx[((size_t)b*L_ + t)*DPROJP + 2048 + g*64 + j0];
    else { v[0]=0; v[1]=0; v[2]=0; v[3]=0; }
    *(i4v*)&in_s[r*64 + j0] = v;
  }
  if (tid < 128){
    if (g < 32){
      float raw = b2f(zx[(rowb + tid)*DPROJP + (DPROJ - NH) + g]);
      float d = softplusf(raw + dtb[g]);
      dt_s[tid] = d;
      dtg[(size_t)(b*NH + g)*L_ + t0 + tid] = d;
      a_s[tid] = d * (-expf(A_log[g]));
    } else {
      dt_s[tid] = 0.f;
      a_s[tid] = 0.f;
    }
  }
  __syncthreads();
  // inclusive prefix-sum of a_s (uniform control flow; result discarded for g>=32)
  #pragma unroll
  for (int d = 1; d < 128; d <<= 1){
    float v = 0.f;
    if (tid < 128 && tid >= d) v = a_s[tid - d];
    __syncthreads();
    if (tid < 128) a_s[tid] += v;
    __syncthreads();
  }
  if (g < 32 && tid < 128)
    acum[((size_t)((b*NH + g)*NC + c))*128 + tid] = a_s[tid];
  {
    int j = tid & 63;
    int ch = g*64 + j;
    float w0 = cw[ch*4+0], w1 = cw[ch*4+1], w2 = cw[ch*4+2], w3 = cw[ch*4+3];
    float bia = cb[ch];
    int tb = tid >> 6;
    #pragma unroll
    for (int it = 0; it < 32; ++it){
      int t = tb + it*4;
      float a = bia
        + w0*b2f(in_s[(t+0)*64 + j]) + w1*b2f(in_s[(t+1)*64 + j])
        + w2*b2f(in_s[(t+2)*64 + j]) + w3*b2f(in_s[(t+3)*64 + j]);
      out_s[osw(t, j)] = f2b(a / (1.f + __expf(-a)));
    }
  }
  __syncthreads();
  if (g < 32){
    for (int i = tid; i < 1024; i += 256){      // 16B columns of Xt
      int j = i >> 4, tb = (i & 15)*8;
      i4v o; u16* ou = (u16*)&o;
      #pragma unroll
      for (int k = 0; k < 8; ++k)
        ou[k] = f2b(b2f(out_s[osw(tb + k, j)]) * dt_s[tb + k]);
      *(i4v*)&Xt[((size_t)((b*NH + g)*HD + j))*L_ + t0 + tb] = o;
    }
  } else {
    int q = g - 32;
    for (int i = tid; i < 1024; i += 256){
      int t = i >> 3, j0 = (i & 7)*8;
      i4v v = *(const i4v*)&out_s[osw(t, j0)];
      if (q < 2) *(i4v*)&Bln[(rowb + t)*DSTATE + q*64 + j0] = v;
      else       *(i4v*)&Cln[(rowb + t)*DSTATE + (q-2)*64 + j0] = v;
    }
    if (q < 2){
      for (int i = tid; i < 1024; i += 256){
        int j = i >> 4, tb = (i & 15)*8;
        i4v o; u16* ou = (u16*)&o;
        #pragma unroll
        for (int k = 0; k < 8; ++k) ou[k] = out_s[osw(tb + k, j)];
        *(i4v*)&Bt[((size_t)(b*DSTATE + q*64 + j))*L_ + t0 + tb] = o;
      }
    }
  }
}

// ---------------- per-chunk states, 4 heads per block (B staged once) ----------------
__global__ __launch_bounds__(256) void k_states(const u16* __restrict__ Xt, const u16* __restrict__ Bt,
    const float* __restrict__ acum, u16* __restrict__ states){
  __shared__ u16 sX[64*128];
  __shared__ u16 sB[128*128];
  __shared__ float dec[128];
  int bid = blockIdx.x;           // ((b*NC + c)*8 + hg)
  int hg = bid & 7, c = (bid >> 3) & 31, b = bid >> 8;
  int tid = threadIdx.x;
  int ln = tid & 63, wid = tid >> 6;
  int wr = wid >> 1, wc = wid & 1;
  const u16* btb = Bt + (size_t)(b*DSTATE)*L_ + c*128;
  for (int i = tid*8; i < 128*128; i += 256*8){
    int n = i >> 7, l0 = i & 127;
    *(i4v*)&sB[swz(n, l0)] = *(const i4v*)&btb[(size_t)n*L_ + l0];
  }
  for (int hh = 0; hh < 4; ++hh){
    int h = hg*4 + hh;
    const float* acg = acum + ((size_t)((b*NH + h)*NC + c))*128;
    if (tid < 128) dec[tid] = __expf(acg[127] - acg[tid]);
    __syncthreads();               // dec+sB ready; prev iter's MFMA reads of sX done
    const u16* xtb = Xt + ((size_t)((b*NH + h)*HD))*L_ + c*128;
    for (int i = tid*8; i < 64*128; i += 256*8){
      int p = i >> 7, l0 = i & 127;
      i4v v = *(const i4v*)&xtb[(size_t)p*L_ + l0];
      const u16* vu = (const u16*)&v;
      i4v o; u16* ou = (u16*)&o;
      #pragma unroll
      for (int j = 0; j < 8; ++j) ou[j] = f2b(b2f(vu[j]) * dec[l0 + j]);
      *(i4v*)&sX[swz(p, l0)] = o;
    }
    __syncthreads();
    f4v acc[2][4] = {};
    #pragma unroll
    for (int kk = 0; kk < 4; ++kk){
      s8v af[2], bfr[4];
      int col = kk*32 + (ln>>4)*8;
      #pragma unroll
      for (int t = 0; t < 2; ++t)
        af[t] = *(const s8v*)&sX[swz(wr*32 + t*16 + (ln&15), col)];
      #pragma unroll
      for (int t = 0; t < 4; ++t)
        bfr[t] = *(const s8v*)&sB[swz(wc*64 + t*16 + (ln&15), col)];
      #pragma unroll
      for (int mt = 0; mt < 2; ++mt)
        #pragma unroll
        for (int nt = 0; nt < 4; ++nt)
          acc[mt][nt] = __builtin_amdgcn_mfma_f32_16x16x32_bf16(af[mt], bfr[nt], acc[mt][nt], 0,0,0);
    }
    u16* out = states + ((size_t)((b*NC + c)*NH + h))*(HD*DSTATE);
    #pragma unroll
    for (int mt = 0; mt < 2; ++mt)
      #pragma unroll
      for (int nt = 0; nt < 4; ++nt){
        int n = wc*64 + nt*16 + (ln&15);
        #pragma unroll
        for (int j = 0; j < 4; ++j){
          int p = wr*32 + mt*16 + (ln>>4)*4 + j;
          out[(size_t)p*DSTATE + n] = f2b(acc[mt][nt][j]);
        }
      }
  }
}

// ---------------- inter-chunk scan (in place, bf16), element-parallel, batched loads ----------------
__global__ __launch_bounds__(256) void k_scan(u16* __restrict__ states, const float* __restrict__ acum){
  int bid = blockIdx.x;            // (b*NH + h)*8 + eb
  int eb = bid & 7;
  int hb = bid >> 3;
  int h = hb & 31, b = hb >> 5;
  int tid = threadIdx.x;
  size_t ebase = (size_t)eb*1024 + (size_t)tid*4;
  size_t hoff = ((size_t)(b*NC*NH + h))*(HD*DSTATE) + ebase;
  float dec[NC];
  #pragma unroll
  for (int c = 0; c < NC; ++c)
    dec[c] = __expf(acum[((size_t)((b*NH + h)*NC + c))*128 + 127]);
  i2v w[NC];
  #pragma unroll
  for (int c = 0; c < NC; ++c)
    w[c] = *(const i2v*)&states[(size_t)c*(NH*HD*DSTATE) + hoff];
  float run[4] = {0.f, 0.f, 0.f, 0.f};
  #pragma unroll
  for (int c = 0; c < NC; ++c){
    u16* wu = (u16*)&w[c];
    #pragma unroll
    for (int j = 0; j < 4; ++j){
      float tmp = b2f(wu[j]);
      wu[j] = f2b(run[j]);
      run[j] = run[j]*dec[c] + tmp;
    }
  }
  #pragma unroll
  for (int c = 0; c < NC; ++c)
    *(i2v*)&states[(size_t)c*(NH*HD*DSTATE) + hoff] = w[c];
}

// ---------------- Y = (C·B^T ⊙ L + diag(D/dt)) · X  +  exp(acum)·(C · prev^T) ----------------
__global__ __launch_bounds__(256) void k_y(const u16* __restrict__ Cln, const u16* __restrict__ Bln,
    const u16* __restrict__ Xt, const u16* __restrict__ prev, const float* __restrict__ acum,
    const float* __restrict__ dtg, const float* __restrict__ Dp, u16* __restrict__ Y){
  __shared__ u16 sC[128*128];
  __shared__ u16 sBS[128*128];   // B tile, then reused to hold masked S
  __shared__ float dt_s[128];
  int bid = blockIdx.x;           // ((b*NC + c)*NH + h)
  int h = bid & 31, c = (bid >> 5) & 31, b = bid >> 10;
  int tid = threadIdx.x;
  size_t rowb = (size_t)b*L_ + c*128;
  const float* acg = acum + ((size_t)((b*NH + h)*NC + c))*128;
  if (tid < 128) dt_s[tid] = dtg[(size_t)(b*NH + h)*L_ + c*128 + tid];
  for (int i = tid*8; i < 128*128; i += 256*8){
    int row = i >> 7, col = i & 127;
    int d = swz(row, col);
    *(i4v*)&sC[d]  = *(const i4v*)&Cln[(rowb + row)*DSTATE + col];
    *(i4v*)&sBS[d] = *(const i4v*)&Bln[(rowb + row)*DSTATE + col];
  }
  __syncthreads();
  int ln = tid & 63, wid = tid >> 6;
  int wr = wid >> 1, wc = wid & 1;
  float Dh = Dp[h];
  f4v aS[4][4] = {};
  #pragma unroll
  for (int kk = 0; kk < 4; ++kk){
    s8v af[4], bfr[4];
    #pragma unroll
    for (int t = 0; t < 4; ++t){
      int col = kk*32 + (ln>>4)*8;
      af[t]  = *(const s8v*)&sC [swz(wr*64 + t*16 + (ln&15), col)];
      bfr[t] = *(const s8v*)&sBS[swz(wc*64 + t*16 + (ln&15), col)];
    }
    #pragma unroll
    for (int mt = 0; mt < 4; ++mt)
      #pragma unroll
      for (int nt = 0; nt < 4; ++nt)
        aS[mt][nt] = __builtin_amdgcn_mfma_f32_16x16x32_bf16(af[mt], bfr[nt], aS[mt][nt], 0,0,0);
  }
  __syncthreads();
  #pragma unroll
  for (int mt = 0; mt < 4; ++mt)
    #pragma unroll
    for (int nt = 0; nt < 4; ++nt){
      int s = wc*64 + nt*16 + (ln&15);
      float as = acg[s];
      #pragma unroll
      for (int j = 0; j < 4; ++j){
        int l = wr*64 + mt*16 + (ln>>4)*4 + j;
        float v = 0.f;
        if (s <= l){
          v = aS[mt][nt][j] * __expf(acg[l] - as);
          if (s == l) v += Dh / dt_s[l];   // folds D*xs into the diagonal
        }
        sBS[swz(l, s)] = f2b(v);
      }
    }
  __syncthreads();
  const u16* xtb = Xt + ((size_t)((b*NH + h)*HD))*L_ + c*128;
  const u16* pv = prev + ((size_t)((b*NC + c)*NH + h))*(HD*DSTATE);
  f4v aD[4][2] = {}, aO[4][2] = {};
  #pragma unroll
  for (int kk = 0; kk < 4; ++kk){
    s8v aSf[4], aCf[4], bXf[2], bPf[2];
    #pragma unroll
    for (int t = 0; t < 4; ++t){
      int col = kk*32 + (ln>>4)*8;
      int row = wr*64 + t*16 + (ln&15);
      aSf[t] = *(const s8v*)&sBS[swz(row, col)];
      aCf[t] = *(const s8v*)&sC[swz(row, col)];
    }
    #pragma unroll
    for (int t = 0; t < 2; ++t){
      int p = wc*32 + t*16 + (ln&15);
      int ko = kk*32 + (ln>>4)*8;
      bXf[t] = *(const s8v*)&xtb[(size_t)p*L_ + ko];
      bPf[t] = *(const s8v*)&pv[(size_t)p*DSTATE + ko];
    }
    #pragma unroll
    for (int mt = 0; mt < 4; ++mt)
      #pragma unroll
      for (int nt = 0; nt < 2; ++nt){
        aD[mt][nt] = __builtin_amdgcn_mfma_f32_16x16x32_bf16(aSf[mt], bXf[nt], aD[mt][nt], 0,0,0);
        aO[mt][nt] = __builtin_amdgcn_mfma_f32_16x16x32_bf16(aCf[mt], bPf[nt], aO[mt][nt], 0,0,0);
      }
  }
  __syncthreads();                 // all waves done reading sC/sBS; reuse sC as out-stage
  #pragma unroll
  for (int mt = 0; mt < 4; ++mt)
    #pragma unroll
    for (int nt = 0; nt < 2; ++nt){
      int p = wc*32 + nt*16 + (ln&15);
      #pragma unroll
      for (int j = 0; j < 4; ++j){
        int l = wr*64 + mt*16 + (ln>>4)*4 + j;
        float ex = __expf(acg[l]);
        float yv = aD[mt][nt][j] + ex*aO[mt][nt][j];
        sC[l*64 + (p ^ ((l & 7) << 3))] = f2b(yv);
      }
    }
  __syncthreads();
  #pragma unroll
  for (int it = 0; it < 4; ++it){
    int idx = (tid + it*256)*8;    // u16 index in 128x64 stage
    int row = idx >> 6, col0 = idx & 63;
    i4v v = *(const i4v*)&sC[row*64 + (col0 ^ ((row & 7) << 3))];
    *(i4v*)&Y[(rowb + row)*DINNER + h*HD + col0] = v;
  }
}

// ---------------- gating + RMSNorm (in place on Y) ----------------
__global__ __launch_bounds__(256) void k_gate(u16* __restrict__ Y, const u16* __restrict__ zx,
                                              const float* __restrict__ rw){
  size_t m = blockIdx.x; int tid = threadIdx.x;
  u16* yrow = Y + m*DINNER + tid*8;
  const u16* zrow = zx + m*DPROJP + tid*8;
  i4v yv = *(const i4v*)yrow;
  i4v zv = *(const i4v*)zrow;
  const u16* yu = (const u16*)&yv;
  const u16* zu = (const u16*)&zv;
  float yg[8]; float ss = 0.f;
  #pragma unroll
  for (int k = 0; k < 8; ++k){
    float z = b2f(zu[k]);
    float g = z / (1.f + __expf(-z));
    float v = b2f(yu[k]) * g;
    yg[k] = v; ss += v*v;
  }
  #pragma unroll
  for (int o = 32; o; o >>= 1) ss += __shfl_down(ss, o);
  __shared__ float r[4];
  if ((tid&63) == 0) r[tid>>6] = ss;
  __syncthreads();
  ss = r[0]+r[1]+r[2]+r[3];
  float rstd = rsqrtf(ss*(1.f/DINNER) + EPSF);
  #pragma unroll
  for (int k = 0; k < 8; ++k)
    yrow[k] = f2b(yg[k]*rstd*rw[tid*8+k]);
}

// ---------------- launch ----------------
extern "C" void kernel_launch(void* const* d_in, const int* in_sizes, int n_in,
                              void* d_out, int out_size, void* d_ws, size_t ws_size,
                              hipStream_t stream){
  const float* x        = (const float*)d_in[0];
  const float* norm_w   = (const float*)d_in[1];
  const float* norm_b   = (const float*)d_in[2];
  const float* in_proj  = (const float*)d_in[3];
  const float* conv_w   = (const float*)d_in[4];
  const float* conv_b   = (const float*)d_in[5];
  const float* dt_bias  = (const float*)d_in[6];
  const float* A_log    = (const float*)d_in[7];
  const float* Dp       = (const float*)d_in[8];
  const float* rms_w    = (const float*)d_in[9];
  const float* out_proj = (const float*)d_in[10];

  char* ws = (char*)d_ws;
  size_t off = 0;
  auto alloc = [&](size_t bytes) -> void* {
    void* p = ws + off;
    off += (bytes + 255) & ~(size_t)255;
    return p;
  };
  u16*   w1b    = (u16*)  alloc((size_t)DPROJP*DMODEL*2);   //  9.2 MB
  u16*   w2b    = (u16*)  alloc((size_t)DMODEL*DINNER*2);   //  4.2 MB
  u16*   xn     = (u16*)  alloc((size_t)ROWS*DMODEL*2);     // 16.8 MB
  u16*   zx     = (u16*)  alloc((size_t)ROWS*DPROJP*2);     // 73.4 MB
  u16*   Xt     = (u16*)  alloc((size_t)B_*NH*HD*L_*2);     // 33.6 MB
  u16*   Bln    = (u16*)  alloc((size_t)ROWS*DSTATE*2);     //  2.1 MB
  u16*   Bt     = (u16*)  alloc((size_t)B_*DSTATE*L_*2);    //  2.1 MB
  u16*   Cln    = (u16*)  alloc((size_t)ROWS*DSTATE*2);     //  2.1 MB
  float* dtg    = (float*)alloc((size_t)B_*NH*L_*4);        //  1.0 MB
  float* acum   = (float*)alloc((size_t)B_*NH*NC*128*4);    //  1.0 MB
  u16*   Y      = (u16*)  alloc((size_t)ROWS*DINNER*2);     // 33.6 MB
  // states/prev (bf16, 33.6 MB) lives in d_out: dead before final GEMM writes d_out.
  u16* states = (u16*)d_out;
  if (off > ws_size){
    k_dbg<<<1, 1, 0, stream>>>((float*)d_out, (float)ws_size);
    return;
  }

  k_pack<<<dim3((unsigned)((NW1 + NW2 + 255)/256)), 256, 0, stream>>>(in_proj, out_proj, w1b, w2b);
  k_ln<<<dim3(ROWS), 256, 0, stream>>>(x, norm_w, norm_b, xn);
  k_gemm_in<<<dim3(ROWS/128, DPROJP/128), 256, 0, stream>>>(xn, w1b, zx,
                                                            DMODEL, DMODEL, DMODEL, DPROJP);
  k_conv<<<dim3(B_*NC*36), 256, 0, stream>>>(zx, conv_w, conv_b, dt_bias, A_log,
                                             Xt, Bln, Bt, Cln, dtg, acum);
  k_states<<<dim3(B_*NC*(NH/4)), 256, 0, stream>>>(Xt, Bt, acum, states);
  k_scan<<<dim3(B_*NH*8), 256, 0, stream>>>(states, acum);
  k_y<<<dim3(B_*NC*NH), 256, 0, stream>>>(Cln, Bln, Xt, states, acum, dtg, Dp, Y);
  k_gate<<<dim3(ROWS), 256, 0, stream>>>(Y, zx, rms_w);
  k_gemm_out<<<dim3(ROWS/128, DMODEL/128), 256, 0, stream>>>(Y, w2b, (float*)d_out, x,
                                                             DINNER, DINNER, DINNER, DMODEL);
}